// Round 7
// baseline (3644.293 us; speedup 1.0000x reference)
//
#include <hip/hip_runtime.h>
#include <stdint.h>

#define TLEN 1024
#define BATCH 64
#define DIMX 128
#define HID 512

typedef __attribute__((ext_vector_type(8))) short short8;
typedef __attribute__((ext_vector_type(4))) float f32x4;
typedef __attribute__((ext_vector_type(4))) unsigned u32x4;

// ---- workspace layout (bytes) ----
#define OFF_WT   0u           // Wt: [2048][640] bf16 = 2,621,440
#define OFF_XBF  2621440u     // xbf: [64][1024][128] bf16 = 16,777,216
#define OFF_HB   19398656u    // hb: [2][64][512] u32 (tagged bf16) = 262,144
#define OFF_ACC  19660800u    // acc: 64
#define OFF_PART 19660864u    // part: [16][64][1024][2] f32 = 8,388,608
#define ZERO_LEN 262208u      // hb + acc

__device__ __forceinline__ unsigned short f2bf(float f) {
  unsigned u = __float_as_uint(f);
  u += 0x7fffu + ((u >> 16) & 1u);
  return (unsigned short)(u >> 16);
}
__device__ __forceinline__ float sigm(float x) { return 1.0f / (1.0f + __expf(-x)); }
__device__ __forceinline__ float tanh_fast(float x) {
  float a = fabsf(x);
  float e = __expf(2.0f * a);
  float t = 1.0f - 2.0f / (e + 1.0f);
  return copysignf(t, x);
}

__device__ __forceinline__ bool tags_bad(const u32x4& r0, const u32x4& r1,
                                         const u32x4& r2, const u32x4& r3,
                                         unsigned tg) {
  unsigned d = (r0[0] ^ tg) | (r0[1] ^ tg) | (r0[2] ^ tg) | (r0[3] ^ tg);
  d |= (r1[0] ^ tg) | (r1[1] ^ tg) | (r1[2] ^ tg) | (r1[3] ^ tg);
  d |= (r2[0] ^ tg) | (r2[1] ^ tg) | (r2[2] ^ tg) | (r2[3] ^ tg);
  d |= (r3[0] ^ tg) | (r3[1] ^ tg) | (r3[2] ^ tg) | (r3[3] ^ tg);
  return (d & 0xFFFFu) != 0u;
}

// ---- x fp32 -> bf16, coalesced ----
__global__ void k_convx(const float4* __restrict__ x4, ushort4* __restrict__ o4) {
  int i = blockIdx.x * 256 + threadIdx.x;
  float4 v = x4[i];
  ushort4 o;
  o.x = f2bf(v.x); o.y = f2bf(v.y); o.z = f2bf(v.z); o.w = f2bf(v.w);
  o4[i] = o;
}

// ---- build Wt[col 0..2047][k 0..639] bf16 = concat(Wx;Wh)^T (proven) ----
__global__ void k_tw(const float* __restrict__ Wx, const float* __restrict__ Wh,
                     unsigned short* __restrict__ Wt) {
  __shared__ float tile[32][65];
  int bk = blockIdx.x;
  int k0 = (bk / 64) * 64;
  int c0 = (bk % 64) * 32;
  int tid = threadIdx.x;
  const float* src = (k0 < 128) ? (Wx + (size_t)k0 * 2048)
                                : (Wh + (size_t)(k0 - 128) * 2048);
#pragma unroll
  for (int p = 0; p < 8; ++p) {
    int i = p * 256 + tid;
    int kk = i >> 5, cc = i & 31;
    tile[cc][kk] = src[(size_t)kk * 2048 + (c0 + cc)];
  }
  __syncthreads();
  int cc = tid >> 3, ch = tid & 7;
  unsigned short tmp[8];
#pragma unroll
  for (int j = 0; j < 8; ++j) tmp[j] = f2bf(tile[cc][ch * 8 + j]);
  uint4 o;
  o.x = (unsigned)tmp[0] | ((unsigned)tmp[1] << 16);
  o.y = (unsigned)tmp[2] | ((unsigned)tmp[3] << 16);
  o.z = (unsigned)tmp[4] | ((unsigned)tmp[5] << 16);
  o.w = (unsigned)tmp[6] | ((unsigned)tmp[7] << 16);
  *(uint4*)(Wt + (size_t)(c0 + cc) * 640 + k0 + ch * 8) = o;
}

// ---- recurrence: 128 WGs = 8 groups(8 rows) x 16 WGs(512thr = 8 waves) ----
// Round-0 proven skeleton + full-window poll: lanes m>=8 (previously duplicate
// row-7 pad reads) now poll the SIBLING half, so one wave's poll covers its
// whole 128-col K-window. The LDS sibling exchange (2 stores + flag release +
// flag spin + 2 loads, ~300cy serial) is replaced by 16 __shfl (~40cy).
// detect==data over all 16 words/lane before any use — safety unchanged.
__global__ __launch_bounds__(512, 1) void k_lstm(
    const unsigned short* __restrict__ xbf,   // [B][T][D] bf16
    const unsigned short* __restrict__ Wt,    // [4H][640] bf16 (B^T layout)
    const float* __restrict__ bias,           // [4H]
    const float* __restrict__ Wo,             // [H][2]
    unsigned* __restrict__ hb,                // [2][B][H] tagged u32
    float* __restrict__ part)                 // [16][B][T][2] logit partials
{
  __shared__ float red[2][4][4][8][32];    // 32 KB z-partial staging

  const int tid  = threadIdx.x;
  const int w    = tid >> 6;      // wave 0..7
  const int kw   = w & 3;         // K-split: x chunk kw, h window kw*128..+127
  const int cg   = w >> 2;        // gate-pair id
  const int lane = tid & 63;
  const int q    = lane >> 4;
  const int m    = lane & 15;
  const int grp  = blockIdx.x & 7;
  const int hj   = blockIdx.x >> 3;  // producer slice 0..15 (cols hj*32..+31)
  const int g0   = grp * 8;

  // ---- pin weight slice in registers (balanced-K mapping, proven) ----
  short8 Bf[5][4];
#pragma unroll
  for (int cc = 0; cc < 5; ++cc) {
#pragma unroll
    for (int j = 0; j < 4; ++j) {
      int gate = cg * 2 + (j >> 1);
      int col = gate * HID + hj * 32 + (j & 1) * 16 + m;
      int k = (cc == 0) ? (kw * 32 + q * 8)
                        : (128 + kw * 128 + (cc - 1) * 32 + q * 8);
      Bf[cc][j] = *(const short8*)(Wt + (size_t)col * 640 + k);
    }
  }

  // gate duty: wave w owns row w; lanes 0..31 own cols
  const int col  = lane & 31;
  const int hcol = hj * 32 + col;
  float c_state = 0.0f;
  const float b_i = bias[0 * HID + hcol];
  const float b_f = bias[1 * HID + hcol];
  const float b_g = bias[2 * HID + hcol];
  const float b_o = bias[3 * HID + hcol];
  const float2 wo = ((const float2*)Wo)[hcol];

  // x A-frag rows: pad rows (m>=8) clamp to 7 — pad A rows never reach used C
  const int arow = (m < 8) ? m : 7;
  const int ab = g0 + arow;

  // full-window poll mapping: lane (q,m) polls row m&7 of half cg^(m>>3)
  const int rowm = m & 7;
  const int hf   = cg ^ (m >> 3);
  const size_t poffF = (size_t)(g0 + rowm) * HID + kw * 128 + hf * 64 + q * 8;

  // shuffle sources: absolute half0 / half1 holders at same q, row m&7
  const int sbase = lane & ~15;
  const int src0 = sbase + rowm + cg * 8;        // lanes holding half 0
  const int src1 = sbase + rowm + (cg ^ 1) * 8;  // lanes holding half 1

  __syncthreads();

#pragma unroll 1
  for (int t = 0; t < TLEN; ++t) {
    const unsigned* hin = hb + (size_t)(t & 1) * (BATCH * HID);
    const int buf = t & 1;

    // ---- x chunk (independent load; issues alongside poll) ----
    short8 a0 = *(const short8*)(xbf + ((size_t)ab * TLEN + t) * DIMX +
                                 kw * 32 + q * 8);

    // ---- full-window batched poll, detect==data (proven asm form) ----
    const unsigned* pb = hin + poffF;
    u32x4 r0, r1, r2, r3;
    {
      const unsigned tg = (unsigned)t & 0xFFFFu;
      int guard = 0;
      for (;;) {
        asm volatile(
            "global_load_dwordx4 %0, %4, off sc0 sc1\n\t"
            "global_load_dwordx4 %1, %4, off offset:16 sc0 sc1\n\t"
            "global_load_dwordx4 %2, %4, off offset:128 sc0 sc1\n\t"
            "global_load_dwordx4 %3, %4, off offset:144 sc0 sc1\n\t"
            "s_waitcnt vmcnt(0)"
            : "=v"(r0), "=v"(r1), "=v"(r2), "=v"(r3)
            : "v"(pb)
            : "memory");
        bool bad = tags_bad(r0, r1, r2, r3, tg);
        if (__ballot(bad) == 0ull || ++guard > (1 << 20)) break;
      }
    }

    // ---- pack lane's (row, half) stretch -> 8 packed words ----
    union U4 { short8 s; unsigned u[4]; };
    U4 F0, F1;
    F0.u[0] = (r0[0] >> 16) | (r0[1] & 0xFFFF0000u);
    F0.u[1] = (r0[2] >> 16) | (r0[3] & 0xFFFF0000u);
    F0.u[2] = (r1[0] >> 16) | (r1[1] & 0xFFFF0000u);
    F0.u[3] = (r1[2] >> 16) | (r1[3] & 0xFFFF0000u);
    F1.u[0] = (r2[0] >> 16) | (r2[1] & 0xFFFF0000u);
    F1.u[1] = (r2[2] >> 16) | (r2[3] & 0xFFFF0000u);
    F1.u[2] = (r3[0] >> 16) | (r3[1] & 0xFFFF0000u);
    F1.u[3] = (r3[2] >> 16) | (r3[3] & 0xFFFF0000u);

    // ---- redistribute to canonical A-frags via shuffles (no LDS hop) ----
    // chunk0 = half0 lo, chunk1 = half0 hi, chunk2 = half1 lo, chunk3 = half1 hi
    U4 A1, A2, A3, A4;
#pragma unroll
    for (int j = 0; j < 4; ++j) {
      A1.u[j] = __shfl(F0.u[j], src0);
      A2.u[j] = __shfl(F1.u[j], src0);
      A3.u[j] = __shfl(F0.u[j], src1);
      A4.u[j] = __shfl(F1.u[j], src1);
    }
    short8 a1 = A1.s, a2 = A2.s, a3 = A3.s, a4 = A4.s;

    // ---- MFMA: z partials for this wave's K-slice, gate pair ----
    f32x4 z0 = {0,0,0,0}, z1 = {0,0,0,0}, z2 = {0,0,0,0}, z3 = {0,0,0,0};
    z0 = __builtin_amdgcn_mfma_f32_16x16x32_bf16(a0, Bf[0][0], z0, 0, 0, 0);
    z1 = __builtin_amdgcn_mfma_f32_16x16x32_bf16(a0, Bf[0][1], z1, 0, 0, 0);
    z2 = __builtin_amdgcn_mfma_f32_16x16x32_bf16(a0, Bf[0][2], z2, 0, 0, 0);
    z3 = __builtin_amdgcn_mfma_f32_16x16x32_bf16(a0, Bf[0][3], z3, 0, 0, 0);
    z0 = __builtin_amdgcn_mfma_f32_16x16x32_bf16(a1, Bf[1][0], z0, 0, 0, 0);
    z1 = __builtin_amdgcn_mfma_f32_16x16x32_bf16(a1, Bf[1][1], z1, 0, 0, 0);
    z2 = __builtin_amdgcn_mfma_f32_16x16x32_bf16(a1, Bf[1][2], z2, 0, 0, 0);
    z3 = __builtin_amdgcn_mfma_f32_16x16x32_bf16(a1, Bf[1][3], z3, 0, 0, 0);
    z0 = __builtin_amdgcn_mfma_f32_16x16x32_bf16(a2, Bf[2][0], z0, 0, 0, 0);
    z1 = __builtin_amdgcn_mfma_f32_16x16x32_bf16(a2, Bf[2][1], z1, 0, 0, 0);
    z2 = __builtin_amdgcn_mfma_f32_16x16x32_bf16(a2, Bf[2][2], z2, 0, 0, 0);
    z3 = __builtin_amdgcn_mfma_f32_16x16x32_bf16(a2, Bf[2][3], z3, 0, 0, 0);
    z0 = __builtin_amdgcn_mfma_f32_16x16x32_bf16(a3, Bf[3][0], z0, 0, 0, 0);
    z1 = __builtin_amdgcn_mfma_f32_16x16x32_bf16(a3, Bf[3][1], z1, 0, 0, 0);
    z2 = __builtin_amdgcn_mfma_f32_16x16x32_bf16(a3, Bf[3][2], z2, 0, 0, 0);
    z3 = __builtin_amdgcn_mfma_f32_16x16x32_bf16(a3, Bf[3][3], z3, 0, 0, 0);
    z0 = __builtin_amdgcn_mfma_f32_16x16x32_bf16(a4, Bf[4][0], z0, 0, 0, 0);
    z1 = __builtin_amdgcn_mfma_f32_16x16x32_bf16(a4, Bf[4][1], z1, 0, 0, 0);
    z2 = __builtin_amdgcn_mfma_f32_16x16x32_bf16(a4, Bf[4][2], z2, 0, 0, 0);
    z3 = __builtin_amdgcn_mfma_f32_16x16x32_bf16(a4, Bf[4][3], z3, 0, 0, 0);

    // ---- stage partials (valid rows in quads 0,1), double-buffered ----
    if (q < 2) {
#pragma unroll
      for (int r = 0; r < 4; ++r) {
        int rw = q * 4 + r;
        red[buf][kw][cg * 2 + 0][rw][0 * 16 + m] = z0[r];
        red[buf][kw][cg * 2 + 0][rw][1 * 16 + m] = z1[r];
        red[buf][kw][cg * 2 + 1][rw][0 * 16 + m] = z2[r];
        red[buf][kw][cg * 2 + 1][rw][1 * 16 + m] = z3[r];
      }
    }
    __syncthreads();   // the only WG rendezvous per step

    // ---- gates: wave w owns row w; lanes 0..31 own cols ----
    if (lane < 32) {
      float zi = b_i + red[buf][0][0][w][col] + red[buf][1][0][w][col]
                     + red[buf][2][0][w][col] + red[buf][3][0][w][col];
      float zf = b_f + red[buf][0][1][w][col] + red[buf][1][1][w][col]
                     + red[buf][2][1][w][col] + red[buf][3][1][w][col];
      float zg = b_g + red[buf][0][2][w][col] + red[buf][1][2][w][col]
                     + red[buf][2][2][w][col] + red[buf][3][2][w][col];
      float zo = b_o + red[buf][0][3][w][col] + red[buf][1][3][w][col]
                     + red[buf][2][3][w][col] + red[buf][3][3][w][col];
      float ig = sigm(zi), fg = sigm(zf), gg = tanh_fast(zg), og = sigm(zo);
      c_state = fg * c_state + ig * gg;
      float hval = og * tanh_fast(c_state);

      // per-lane tagged store; 32 lanes = one 128B coalesced transaction
      unsigned hword = ((unsigned)f2bf(hval) << 16) | (unsigned)((t + 1) & 0xFFFF);
      unsigned* dst = hb + (size_t)((t + 1) & 1) * (BATCH * HID) +
                      (size_t)(g0 + w) * HID + hcol;
      asm volatile("global_store_dword %0, %1, off sc0 sc1"
                   :: "v"(dst), "v"(hword) : "memory");

      // logit partial -> private slot (no atomics, no contention)
      float p0 = hval * wo.x, p1 = hval * wo.y;
      p0 += __shfl_xor(p0, 16); p1 += __shfl_xor(p1, 16);
      p0 += __shfl_xor(p0, 8);  p1 += __shfl_xor(p1, 8);
      p0 += __shfl_xor(p0, 4);  p1 += __shfl_xor(p1, 4);
      p0 += __shfl_xor(p0, 2);  p1 += __shfl_xor(p1, 2);
      p0 += __shfl_xor(p0, 1);  p1 += __shfl_xor(p1, 1);
      if (lane == 0) {
        float2 pv; pv.x = p0; pv.y = p1;
        *(float2*)(part + (((size_t)hj * BATCH + (g0 + w)) * TLEN + t) * 2) = pv;
      }
    }
  }
}

// ---- partials -> logits -> softmax probs + NLL ----
__global__ void k_out2(float* __restrict__ out, const float* __restrict__ bo,
                       const int* __restrict__ labels,
                       const float2* __restrict__ part,
                       float* __restrict__ acc) {
  __shared__ float sred[4];
  int i = blockIdx.x * 256 + threadIdx.x;   // 0..65535 = b*T + t
  float l0 = bo[0], l1 = bo[1];
#pragma unroll
  for (int hj = 0; hj < 16; ++hj) {
    float2 p = part[(size_t)hj * (BATCH * TLEN) + i];
    l0 += p.x; l1 += p.y;
  }
  float mx = fmaxf(l0, l1);
  float e0 = __expf(l0 - mx), e1 = __expf(l1 - mx);
  float s = e0 + e1, inv = 1.0f / s;
  out[(size_t)i * 2 + 0] = e0 * inv;
  out[(size_t)i * 2 + 1] = e1 * inv;
  int lab = labels[i];
  float nll = __logf(s) - ((lab ? l1 : l0) - mx);
#pragma unroll
  for (int off = 32; off >= 1; off >>= 1) nll += __shfl_xor(nll, off);
  if ((threadIdx.x & 63) == 0) sred[threadIdx.x >> 6] = nll;
  __syncthreads();
  if (threadIdx.x == 0)
    atomicAdd(acc, sred[0] + sred[1] + sred[2] + sred[3]);
}

__global__ void k_fin(const float* __restrict__ acc, float* __restrict__ out) {
  out[BATCH * TLEN * 2] = acc[0] * (1.0f / (float)(BATCH * TLEN));
}

extern "C" void kernel_launch(void* const* d_in, const int* in_sizes, int n_in,
                              void* d_out, int out_size, void* d_ws, size_t ws_size,
                              hipStream_t stream) {
  const float* x      = (const float*)d_in[0];
  const int*   labels = (const int*)d_in[1];
  const float* Wx     = (const float*)d_in[2];
  const float* Wh     = (const float*)d_in[3];
  const float* b      = (const float*)d_in[4];
  const float* Wo     = (const float*)d_in[5];
  const float* bo     = (const float*)d_in[6];
  float* out = (float*)d_out;
  char* ws = (char*)d_ws;

  unsigned short* Wt  = (unsigned short*)(ws + OFF_WT);
  unsigned short* xbf = (unsigned short*)(ws + OFF_XBF);
  unsigned*       hb  = (unsigned*)(ws + OFF_HB);
  float*          acc = (float*)(ws + OFF_ACC);
  float*          part = (float*)(ws + OFF_PART);

  // hb zero => h_0 = 0 with tag 0 (self-validating); acc zero
  hipMemsetAsync(ws + OFF_HB, 0, ZERO_LEN, stream);
  k_convx<<<8192, 256, 0, stream>>>((const float4*)x, (ushort4*)xbf);
  k_tw<<<640, 256, 0, stream>>>(Wx, Wh, Wt);
  k_lstm<<<128, 512, 0, stream>>>(xbf, Wt, b, Wo, hb, part);
  k_out2<<<256, 256, 0, stream>>>(out, bo, labels, (const float2*)part, acc);
  k_fin<<<1, 1, 0, stream>>>(acc, out);
}

// Round 8
// 2747.694 us; speedup vs baseline: 1.3263x; 1.3263x over previous
//
#include <hip/hip_runtime.h>
#include <stdint.h>

#define TLEN 1024
#define BATCH 64
#define DIMX 128
#define HID 512

typedef __attribute__((ext_vector_type(8))) short short8;
typedef __attribute__((ext_vector_type(4))) float f32x4;
typedef __attribute__((ext_vector_type(4))) unsigned u32x4;

// ---- workspace layout (bytes) ----
#define OFF_WT   0u           // Wt: [2048][640] bf16 = 2,621,440
#define OFF_XBF  2621440u     // xbf: [64][1024][128] bf16 = 16,777,216
#define OFF_HB   19398656u    // hb: [2][64][512] u32 (tagged bf16) = 262,144
#define OFF_ACC  19660800u    // acc: 64
#define OFF_PART 19660864u    // part: [16][64][1024][2] f32 = 8,388,608
#define ZERO_LEN 262208u      // hb + acc

__device__ __forceinline__ unsigned short f2bf(float f) {
  unsigned u = __float_as_uint(f);
  u += 0x7fffu + ((u >> 16) & 1u);
  return (unsigned short)(u >> 16);
}
__device__ __forceinline__ float sigm(float x) { return 1.0f / (1.0f + __expf(-x)); }
__device__ __forceinline__ float tanh_fast(float x) {
  float a = fabsf(x);
  float e = __expf(2.0f * a);
  float t = 1.0f - 2.0f / (e + 1.0f);
  return copysignf(t, x);
}

__device__ __forceinline__ bool tags_bad(const u32x4& r0, const u32x4& r1,
                                         const u32x4& r2, const u32x4& r3,
                                         unsigned tg) {
  unsigned d = (r0[0] ^ tg) | (r0[1] ^ tg) | (r0[2] ^ tg) | (r0[3] ^ tg);
  d |= (r1[0] ^ tg) | (r1[1] ^ tg) | (r1[2] ^ tg) | (r1[3] ^ tg);
  d |= (r2[0] ^ tg) | (r2[1] ^ tg) | (r2[2] ^ tg) | (r2[3] ^ tg);
  d |= (r3[0] ^ tg) | (r3[1] ^ tg) | (r3[2] ^ tg) | (r3[3] ^ tg);
  return (d & 0xFFFFu) != 0u;
}

// ---- x fp32 -> bf16, coalesced ----
__global__ void k_convx(const float4* __restrict__ x4, ushort4* __restrict__ o4) {
  int i = blockIdx.x * 256 + threadIdx.x;
  float4 v = x4[i];
  ushort4 o;
  o.x = f2bf(v.x); o.y = f2bf(v.y); o.z = f2bf(v.z); o.w = f2bf(v.w);
  o4[i] = o;
}

// ---- build Wt[col 0..2047][k 0..639] bf16 = concat(Wx;Wh)^T (proven) ----
__global__ void k_tw(const float* __restrict__ Wx, const float* __restrict__ Wh,
                     unsigned short* __restrict__ Wt) {
  __shared__ float tile[32][65];
  int bk = blockIdx.x;
  int k0 = (bk / 64) * 64;
  int c0 = (bk % 64) * 32;
  int tid = threadIdx.x;
  const float* src = (k0 < 128) ? (Wx + (size_t)k0 * 2048)
                                : (Wh + (size_t)(k0 - 128) * 2048);
#pragma unroll
  for (int p = 0; p < 8; ++p) {
    int i = p * 256 + tid;
    int kk = i >> 5, cc = i & 31;
    tile[cc][kk] = src[(size_t)kk * 2048 + (c0 + cc)];
  }
  __syncthreads();
  int cc = tid >> 3, ch = tid & 7;
  unsigned short tmp[8];
#pragma unroll
  for (int j = 0; j < 8; ++j) tmp[j] = f2bf(tile[cc][ch * 8 + j]);
  uint4 o;
  o.x = (unsigned)tmp[0] | ((unsigned)tmp[1] << 16);
  o.y = (unsigned)tmp[2] | ((unsigned)tmp[3] << 16);
  o.z = (unsigned)tmp[4] | ((unsigned)tmp[5] << 16);
  o.w = (unsigned)tmp[6] | ((unsigned)tmp[7] << 16);
  *(uint4*)(Wt + (size_t)(c0 + cc) * 640 + k0 + ch * 8) = o;
}

// ---- recurrence: 128 WGs = 8 groups(8 rows) x 16 WGs(512thr = 8 waves) ----
// 8-way K-split, exchange-free: wave j polls its OWN 64-col h window
// (2 producers, identical proven poll asm + pack as round 0) and computes
// partials for ALL 128 of the WG's gate-cols over K-slice j. No LDS
// sibling exchange / flags / shuffles. Cross-K reduce via red (8 slices)
// + the single per-step barrier. x-chunks on waves 0-3 (as before).
__global__ __launch_bounds__(512, 1) void k_lstm(
    const unsigned short* __restrict__ xbf,   // [B][T][D] bf16
    const unsigned short* __restrict__ Wt,    // [4H][640] bf16 (B^T layout)
    const float* __restrict__ bias,           // [4H]
    const float* __restrict__ Wo,             // [H][2]
    unsigned* __restrict__ hb,                // [2][B][H] tagged u32
    float* __restrict__ part)                 // [16][B][T][2] logit partials
{
  __shared__ float red[2][8][4][8][32];    // 64 KB (buf, kslice, gate, row, col)

  const int tid  = threadIdx.x;
  const int w    = tid >> 6;      // wave 0..7 = K-slice id
  const int lane = tid & 63;
  const int q    = lane >> 4;
  const int m    = lane & 15;
  const int grp  = blockIdx.x & 7;
  const int hj   = blockIdx.x >> 3;  // producer slice 0..15 (cols hj*32..+31)
  const int g0   = grp * 8;

  // ---- pin weight slice in registers ----
  // wave w: h K-slice cols w*64..+64 (k = 128 + w*64 + c*32), all 8 N-frags;
  // waves 0-3 additionally x chunk k = w*32.
  short8 Bh[8][2];
  short8 Bx[8];
#pragma unroll
  for (int f = 0; f < 8; ++f) {
    int gate = f >> 1;
    int colg = gate * HID + hj * 32 + (f & 1) * 16 + m;
    const unsigned short* wc = Wt + (size_t)colg * 640;
#pragma unroll
    for (int c = 0; c < 2; ++c)
      Bh[f][c] = *(const short8*)(wc + 128 + w * 64 + c * 32 + q * 8);
    if (w < 4) Bx[f] = *(const short8*)(wc + w * 32 + q * 8);
  }

  // gate duty: wave w owns row w; lanes 0..31 own cols
  const int col  = lane & 31;
  const int hcol = hj * 32 + col;
  float c_state = 0.0f;
  const float b_i = bias[0 * HID + hcol];
  const float b_f = bias[1 * HID + hcol];
  const float b_g = bias[2 * HID + hcol];
  const float b_o = bias[3 * HID + hcol];
  const float2 wo = ((const float2*)Wo)[hcol];

  const int arow = (m < 8) ? m : 7;   // clamp pad rows (coalesced dup = free)
  const int ab = g0 + arow;
  // poll: wave w's own 64-col window at cols w*64 (2 producer WGs)
  const size_t poff = (size_t)ab * HID + w * 64 + q * 8;

  __syncthreads();

#pragma unroll 1
  for (int t = 0; t < TLEN; ++t) {
    const unsigned* hin = hb + (size_t)(t & 1) * (BATCH * HID);
    const int buf = t & 1;

    // ---- x chunk (issued before poll; latency hides under poll vmcnt) ----
    short8 a0;
    if (w < 4)
      a0 = *(const short8*)(xbf + ((size_t)ab * TLEN + t) * DIMX +
                            w * 32 + q * 8);

    // ---- own-window batched poll, detect==data (proven asm form) ----
    const unsigned* pb = hin + poff;
    u32x4 r0, r1, r2, r3;
    {
      const unsigned tg = (unsigned)t & 0xFFFFu;
      int guard = 0;
      for (;;) {
        asm volatile(
            "global_load_dwordx4 %0, %4, off sc0 sc1\n\t"
            "global_load_dwordx4 %1, %4, off offset:16 sc0 sc1\n\t"
            "global_load_dwordx4 %2, %4, off offset:128 sc0 sc1\n\t"
            "global_load_dwordx4 %3, %4, off offset:144 sc0 sc1\n\t"
            "s_waitcnt vmcnt(0)"
            : "=v"(r0), "=v"(r1), "=v"(r2), "=v"(r3)
            : "v"(pb)
            : "memory");
        bool bad = tags_bad(r0, r1, r2, r3, tg);
        if (__ballot(bad) == 0ull || ++guard > (1 << 20)) break;
      }
    }

    // ---- pack own window -> 2 A-frags (cols w*64..+32, w*64+32..+64) ----
    short8 af0, af1;
    {
      union { short8 s; unsigned u[4]; } pk;
      pk.u[0] = (r0[0] >> 16) | (r0[1] & 0xFFFF0000u);
      pk.u[1] = (r0[2] >> 16) | (r0[3] & 0xFFFF0000u);
      pk.u[2] = (r1[0] >> 16) | (r1[1] & 0xFFFF0000u);
      pk.u[3] = (r1[2] >> 16) | (r1[3] & 0xFFFF0000u);
      af0 = pk.s;
      pk.u[0] = (r2[0] >> 16) | (r2[1] & 0xFFFF0000u);
      pk.u[1] = (r2[2] >> 16) | (r2[3] & 0xFFFF0000u);
      pk.u[2] = (r3[0] >> 16) | (r3[1] & 0xFFFF0000u);
      pk.u[3] = (r3[2] >> 16) | (r3[3] & 0xFFFF0000u);
      af1 = pk.s;
    }

    // ---- MFMA: partials for all 128 WG gate-cols over this K-slice ----
    f32x4 z[8];
#pragma unroll
    for (int f = 0; f < 8; ++f) z[f] = (f32x4){0.f, 0.f, 0.f, 0.f};
    if (w < 4) {
#pragma unroll
      for (int f = 0; f < 8; ++f)
        z[f] = __builtin_amdgcn_mfma_f32_16x16x32_bf16(a0, Bx[f], z[f], 0, 0, 0);
    }
#pragma unroll
    for (int f = 0; f < 8; ++f)
      z[f] = __builtin_amdgcn_mfma_f32_16x16x32_bf16(af0, Bh[f][0], z[f], 0, 0, 0);
#pragma unroll
    for (int f = 0; f < 8; ++f)
      z[f] = __builtin_amdgcn_mfma_f32_16x16x32_bf16(af1, Bh[f][1], z[f], 0, 0, 0);

    // ---- stage partials (valid rows in quads 0,1), double-buffered ----
    if (q < 2) {
#pragma unroll
      for (int f = 0; f < 8; ++f) {
#pragma unroll
        for (int r = 0; r < 4; ++r)
          red[buf][w][f >> 1][q * 4 + r][(f & 1) * 16 + m] = z[f][r];
      }
    }
    __syncthreads();   // the only WG rendezvous per step

    // ---- gates: wave w owns row w; lanes 0..31 own cols ----
    if (lane < 32) {
      float zi = b_i, zf = b_f, zg = b_g, zo = b_o;
#pragma unroll
      for (int jj = 0; jj < 8; ++jj) {
        zi += red[buf][jj][0][w][col];
        zf += red[buf][jj][1][w][col];
        zg += red[buf][jj][2][w][col];
        zo += red[buf][jj][3][w][col];
      }
      float ig = sigm(zi), fg = sigm(zf), gg = tanh_fast(zg), og = sigm(zo);
      c_state = fg * c_state + ig * gg;
      float hval = og * tanh_fast(c_state);

      // per-lane tagged store; 32 lanes = one 128B coalesced transaction
      unsigned hword = ((unsigned)f2bf(hval) << 16) | (unsigned)((t + 1) & 0xFFFF);
      unsigned* dst = hb + (size_t)((t + 1) & 1) * (BATCH * HID) +
                      (size_t)(g0 + w) * HID + hcol;
      asm volatile("global_store_dword %0, %1, off sc0 sc1"
                   :: "v"(dst), "v"(hword) : "memory");

      // logit partial -> private slot (no atomics, no contention)
      float p0 = hval * wo.x, p1 = hval * wo.y;
      p0 += __shfl_xor(p0, 16); p1 += __shfl_xor(p1, 16);
      p0 += __shfl_xor(p0, 8);  p1 += __shfl_xor(p1, 8);
      p0 += __shfl_xor(p0, 4);  p1 += __shfl_xor(p1, 4);
      p0 += __shfl_xor(p0, 2);  p1 += __shfl_xor(p1, 2);
      p0 += __shfl_xor(p0, 1);  p1 += __shfl_xor(p1, 1);
      if (lane == 0) {
        float2 pv; pv.x = p0; pv.y = p1;
        *(float2*)(part + (((size_t)hj * BATCH + (g0 + w)) * TLEN + t) * 2) = pv;
      }
    }
  }
}

// ---- partials -> logits -> softmax probs + NLL ----
__global__ void k_out2(float* __restrict__ out, const float* __restrict__ bo,
                       const int* __restrict__ labels,
                       const float2* __restrict__ part,
                       float* __restrict__ acc) {
  __shared__ float sred[4];
  int i = blockIdx.x * 256 + threadIdx.x;   // 0..65535 = b*T + t
  float l0 = bo[0], l1 = bo[1];
#pragma unroll
  for (int hj = 0; hj < 16; ++hj) {
    float2 p = part[(size_t)hj * (BATCH * TLEN) + i];
    l0 += p.x; l1 += p.y;
  }
  float mx = fmaxf(l0, l1);
  float e0 = __expf(l0 - mx), e1 = __expf(l1 - mx);
  float s = e0 + e1, inv = 1.0f / s;
  out[(size_t)i * 2 + 0] = e0 * inv;
  out[(size_t)i * 2 + 1] = e1 * inv;
  int lab = labels[i];
  float nll = __logf(s) - ((lab ? l1 : l0) - mx);
#pragma unroll
  for (int off = 32; off >= 1; off >>= 1) nll += __shfl_xor(nll, off);
  if ((threadIdx.x & 63) == 0) sred[threadIdx.x >> 6] = nll;
  __syncthreads();
  if (threadIdx.x == 0)
    atomicAdd(acc, sred[0] + sred[1] + sred[2] + sred[3]);
}

__global__ void k_fin(const float* __restrict__ acc, float* __restrict__ out) {
  out[BATCH * TLEN * 2] = acc[0] * (1.0f / (float)(BATCH * TLEN));
}

extern "C" void kernel_launch(void* const* d_in, const int* in_sizes, int n_in,
                              void* d_out, int out_size, void* d_ws, size_t ws_size,
                              hipStream_t stream) {
  const float* x      = (const float*)d_in[0];
  const int*   labels = (const int*)d_in[1];
  const float* Wx     = (const float*)d_in[2];
  const float* Wh     = (const float*)d_in[3];
  const float* b      = (const float*)d_in[4];
  const float* Wo     = (const float*)d_in[5];
  const float* bo     = (const float*)d_in[6];
  float* out = (float*)d_out;
  char* ws = (char*)d_ws;

  unsigned short* Wt  = (unsigned short*)(ws + OFF_WT);
  unsigned short* xbf = (unsigned short*)(ws + OFF_XBF);
  unsigned*       hb  = (unsigned*)(ws + OFF_HB);
  float*          acc = (float*)(ws + OFF_ACC);
  float*          part = (float*)(ws + OFF_PART);

  // hb zero => h_0 = 0 with tag 0 (self-validating); acc zero
  hipMemsetAsync(ws + OFF_HB, 0, ZERO_LEN, stream);
  k_convx<<<8192, 256, 0, stream>>>((const float4*)x, (ushort4*)xbf);
  k_tw<<<640, 256, 0, stream>>>(Wx, Wh, Wt);
  k_lstm<<<128, 512, 0, stream>>>(xbf, Wt, b, Wo, hb, part);
  k_out2<<<256, 256, 0, stream>>>(out, bo, labels, (const float2*)part, acc);
  k_fin<<<1, 1, 0, stream>>>(acc, out);
}

// Round 9
// 2691.297 us; speedup vs baseline: 1.3541x; 1.0210x over previous
//
#include <hip/hip_runtime.h>
#include <stdint.h>

#define TLEN 1024
#define BATCH 64
#define DIMX 128
#define HID 512

typedef __attribute__((ext_vector_type(8))) short short8;
typedef __attribute__((ext_vector_type(4))) float f32x4;
typedef __attribute__((ext_vector_type(4))) unsigned u32x4;

// ---- workspace layout (bytes) ----
#define OFF_WT   0u           // Wt: [2048][640] bf16 = 2,621,440
#define OFF_XBF  2621440u     // xbf: [64][1024][128] bf16 = 16,777,216
#define OFF_HB   19398656u    // hb: [2][64][512] u32 (tagged bf16) = 262,144
#define OFF_ACC  19660800u    // acc: 64
#define OFF_PART 19660864u    // part: [16][64][1024][2] f32 = 8,388,608
#define ZERO_LEN 262208u      // hb + acc

__device__ __forceinline__ unsigned short f2bf(float f) {
  unsigned u = __float_as_uint(f);
  u += 0x7fffu + ((u >> 16) & 1u);
  return (unsigned short)(u >> 16);
}
__device__ __forceinline__ float sigm(float x) { return 1.0f / (1.0f + __expf(-x)); }
__device__ __forceinline__ float tanh_fast(float x) {
  float a = fabsf(x);
  float e = __expf(2.0f * a);
  float t = 1.0f - 2.0f / (e + 1.0f);
  return copysignf(t, x);
}

__device__ __forceinline__ bool tags_bad(const u32x4& r0, const u32x4& r1,
                                         const u32x4& r2, const u32x4& r3,
                                         unsigned tg) {
  unsigned d = (r0[0] ^ tg) | (r0[1] ^ tg) | (r0[2] ^ tg) | (r0[3] ^ tg);
  d |= (r1[0] ^ tg) | (r1[1] ^ tg) | (r1[2] ^ tg) | (r1[3] ^ tg);
  d |= (r2[0] ^ tg) | (r2[1] ^ tg) | (r2[2] ^ tg) | (r2[3] ^ tg);
  d |= (r3[0] ^ tg) | (r3[1] ^ tg) | (r3[2] ^ tg) | (r3[3] ^ tg);
  return (d & 0xFFFFu) != 0u;
}

// ---- x fp32 -> bf16, coalesced ----
__global__ void k_convx(const float4* __restrict__ x4, ushort4* __restrict__ o4) {
  int i = blockIdx.x * 256 + threadIdx.x;
  float4 v = x4[i];
  ushort4 o;
  o.x = f2bf(v.x); o.y = f2bf(v.y); o.z = f2bf(v.z); o.w = f2bf(v.w);
  o4[i] = o;
}

// ---- build Wt[col 0..2047][k 0..639] bf16 = concat(Wx;Wh)^T (proven) ----
__global__ void k_tw(const float* __restrict__ Wx, const float* __restrict__ Wh,
                     unsigned short* __restrict__ Wt) {
  __shared__ float tile[32][65];
  int bk = blockIdx.x;
  int k0 = (bk / 64) * 64;
  int c0 = (bk % 64) * 32;
  int tid = threadIdx.x;
  const float* src = (k0 < 128) ? (Wx + (size_t)k0 * 2048)
                                : (Wh + (size_t)(k0 - 128) * 2048);
#pragma unroll
  for (int p = 0; p < 8; ++p) {
    int i = p * 256 + tid;
    int kk = i >> 5, cc = i & 31;
    tile[cc][kk] = src[(size_t)kk * 2048 + (c0 + cc)];
  }
  __syncthreads();
  int cc = tid >> 3, ch = tid & 7;
  unsigned short tmp[8];
#pragma unroll
  for (int j = 0; j < 8; ++j) tmp[j] = f2bf(tile[cc][ch * 8 + j]);
  uint4 o;
  o.x = (unsigned)tmp[0] | ((unsigned)tmp[1] << 16);
  o.y = (unsigned)tmp[2] | ((unsigned)tmp[3] << 16);
  o.z = (unsigned)tmp[4] | ((unsigned)tmp[5] << 16);
  o.w = (unsigned)tmp[6] | ((unsigned)tmp[7] << 16);
  *(uint4*)(Wt + (size_t)(c0 + cc) * 640 + k0 + ch * 8) = o;
}

// ---- recurrence: 128 WGs = 8 groups(8 rows) x 16 WGs(512thr = 8 waves) ----
// R7 exchange-free 8-way K-split skeleton (proven, 2706us) +
//  - s_sleep(2) backoff after failed spin check (LLC decongestion)
//  - quick 4-word pre-check, full 16-word detect==data before any use
//  - half-wave gate split: upper lanes compute g/o gates, shfl to lower
__global__ __launch_bounds__(512, 1) void k_lstm(
    const unsigned short* __restrict__ xbf,   // [B][T][D] bf16
    const unsigned short* __restrict__ Wt,    // [4H][640] bf16 (B^T layout)
    const float* __restrict__ bias,           // [4H]
    const float* __restrict__ Wo,             // [H][2]
    unsigned* __restrict__ hb,                // [2][B][H] tagged u32
    float* __restrict__ part)                 // [16][B][T][2] logit partials
{
  __shared__ float red[2][8][4][8][32];    // 64 KB (buf, kslice, gate, row, col)

  const int tid  = threadIdx.x;
  const int w    = tid >> 6;      // wave 0..7 = K-slice id
  const int lane = tid & 63;
  const int q    = lane >> 4;
  const int m    = lane & 15;
  const int grp  = blockIdx.x & 7;
  const int hj   = blockIdx.x >> 3;  // producer slice 0..15 (cols hj*32..+31)
  const int g0   = grp * 8;

  // ---- pin weight slice in registers ----
  short8 Bh[8][2];
  short8 Bx[8];
#pragma unroll
  for (int f = 0; f < 8; ++f) {
    int gate = f >> 1;
    int colg = gate * HID + hj * 32 + (f & 1) * 16 + m;
    const unsigned short* wc = Wt + (size_t)colg * 640;
#pragma unroll
    for (int c = 0; c < 2; ++c)
      Bh[f][c] = *(const short8*)(wc + 128 + w * 64 + c * 32 + q * 8);
    if (w < 4) Bx[f] = *(const short8*)(wc + w * 32 + q * 8);
  }

  // gate duty: wave w owns row w; lower half lanes own cols for i/f,
  // upper half same cols for g/o (split-serial-chain gates)
  const int col  = lane & 31;
  const int hcol = hj * 32 + col;
  const int up   = lane >> 5;          // 0 = i/f half, 1 = g/o half
  float c_state = 0.0f;
  const float b_a = up ? bias[2 * HID + hcol] : bias[0 * HID + hcol]; // zg : zi
  const float b_b = up ? bias[3 * HID + hcol] : bias[1 * HID + hcol]; // zo : zf
  const int ga = up ? 2 : 0;
  const int gb = up ? 3 : 1;
  const float2 wo = ((const float2*)Wo)[hcol];

  const int arow = (m < 8) ? m : 7;   // clamp pad rows (coalesced dup = free)
  const int ab = g0 + arow;
  // poll: wave w's own 64-col window at cols w*64 (2 producer WGs)
  const size_t poff = (size_t)ab * HID + w * 64 + q * 8;

  __syncthreads();

#pragma unroll 1
  for (int t = 0; t < TLEN; ++t) {
    const unsigned* hin = hb + (size_t)(t & 1) * (BATCH * HID);
    const int buf = t & 1;

    // ---- x chunk (issued before poll; latency hides under poll vmcnt) ----
    short8 a0;
    if (w < 4)
      a0 = *(const short8*)(xbf + ((size_t)ab * TLEN + t) * DIMX +
                            w * 32 + q * 8);

    // ---- own-window batched poll, detect==data (proven asm form) ----
    // quick 4-word pre-check trims spin VALU; s_sleep(2) after a failed
    // round decongests the LLC (polls contend with the stores they await).
    const unsigned* pb = hin + poff;
    u32x4 r0, r1, r2, r3;
    {
      const unsigned tg = (unsigned)t & 0xFFFFu;
      int guard = 0;
      for (;;) {
        asm volatile(
            "global_load_dwordx4 %0, %4, off sc0 sc1\n\t"
            "global_load_dwordx4 %1, %4, off offset:16 sc0 sc1\n\t"
            "global_load_dwordx4 %2, %4, off offset:128 sc0 sc1\n\t"
            "global_load_dwordx4 %3, %4, off offset:144 sc0 sc1\n\t"
            "s_waitcnt vmcnt(0)"
            : "=v"(r0), "=v"(r1), "=v"(r2), "=v"(r3)
            : "v"(pb)
            : "memory");
        unsigned dq = (r0[0] ^ tg) | (r1[0] ^ tg) | (r2[0] ^ tg) | (r3[0] ^ tg);
        bool qbad = (dq & 0xFFFFu) != 0u;
        if (__ballot(qbad) == 0ull) {
          bool bad = tags_bad(r0, r1, r2, r3, tg);   // full check before ANY use
          if (__ballot(bad) == 0ull) break;
        }
        if (++guard > (1 << 20)) break;
        __builtin_amdgcn_s_sleep(2);
      }
    }

    // ---- pack own window -> 2 A-frags (cols w*64..+32, w*64+32..+64) ----
    short8 af0, af1;
    {
      union { short8 s; unsigned u[4]; } pk;
      pk.u[0] = (r0[0] >> 16) | (r0[1] & 0xFFFF0000u);
      pk.u[1] = (r0[2] >> 16) | (r0[3] & 0xFFFF0000u);
      pk.u[2] = (r1[0] >> 16) | (r1[1] & 0xFFFF0000u);
      pk.u[3] = (r1[2] >> 16) | (r1[3] & 0xFFFF0000u);
      af0 = pk.s;
      pk.u[0] = (r2[0] >> 16) | (r2[1] & 0xFFFF0000u);
      pk.u[1] = (r2[2] >> 16) | (r2[3] & 0xFFFF0000u);
      pk.u[2] = (r3[0] >> 16) | (r3[1] & 0xFFFF0000u);
      pk.u[3] = (r3[2] >> 16) | (r3[3] & 0xFFFF0000u);
      af1 = pk.s;
    }

    // ---- MFMA: partials for all 128 WG gate-cols over this K-slice ----
    f32x4 z[8];
#pragma unroll
    for (int f = 0; f < 8; ++f) z[f] = (f32x4){0.f, 0.f, 0.f, 0.f};
    if (w < 4) {
#pragma unroll
      for (int f = 0; f < 8; ++f)
        z[f] = __builtin_amdgcn_mfma_f32_16x16x32_bf16(a0, Bx[f], z[f], 0, 0, 0);
    }
#pragma unroll
    for (int f = 0; f < 8; ++f)
      z[f] = __builtin_amdgcn_mfma_f32_16x16x32_bf16(af0, Bh[f][0], z[f], 0, 0, 0);
#pragma unroll
    for (int f = 0; f < 8; ++f)
      z[f] = __builtin_amdgcn_mfma_f32_16x16x32_bf16(af1, Bh[f][1], z[f], 0, 0, 0);

    // ---- stage partials (valid rows in quads 0,1), double-buffered ----
    if (q < 2) {
#pragma unroll
      for (int f = 0; f < 8; ++f) {
#pragma unroll
        for (int r = 0; r < 4; ++r)
          red[buf][w][f >> 1][q * 4 + r][(f & 1) * 16 + m] = z[f][r];
      }
    }
    __syncthreads();   // the only WG rendezvous per step

    // ---- gates, split across half-waves: lower = i/f, upper = g/o ----
    {
      float za = b_a, zb = b_b;
#pragma unroll
      for (int jj = 0; jj < 8; ++jj) {
        za += red[buf][jj][ga][w][col];
        zb += red[buf][jj][gb][w][col];
      }
      // lower: va=ig, vb=fg ; upper: va=gg, vb=og
      float va = up ? tanh_fast(za) : sigm(za);
      float vb = sigm(zb);
      float gg = __shfl(va, col + 32);   // executed by all lanes
      float og = __shfl(vb, col + 32);

      if (lane < 32) {
        c_state = vb * c_state + va * gg;
        float hval = og * tanh_fast(c_state);

        // per-lane tagged store; 32 lanes = one 128B coalesced transaction
        unsigned hword = ((unsigned)f2bf(hval) << 16) |
                         (unsigned)((t + 1) & 0xFFFF);
        unsigned* dst = hb + (size_t)((t + 1) & 1) * (BATCH * HID) +
                        (size_t)(g0 + w) * HID + hcol;
        asm volatile("global_store_dword %0, %1, off sc0 sc1"
                     :: "v"(dst), "v"(hword) : "memory");

        // logit partial -> private slot (no atomics, no contention)
        float p0 = hval * wo.x, p1 = hval * wo.y;
        p0 += __shfl_xor(p0, 16); p1 += __shfl_xor(p1, 16);
        p0 += __shfl_xor(p0, 8);  p1 += __shfl_xor(p1, 8);
        p0 += __shfl_xor(p0, 4);  p1 += __shfl_xor(p1, 4);
        p0 += __shfl_xor(p0, 2);  p1 += __shfl_xor(p1, 2);
        p0 += __shfl_xor(p0, 1);  p1 += __shfl_xor(p1, 1);
        if (lane == 0) {
          float2 pv; pv.x = p0; pv.y = p1;
          *(float2*)(part + (((size_t)hj * BATCH + (g0 + w)) * TLEN + t) * 2) = pv;
        }
      }
    }
  }
}

// ---- partials -> logits -> softmax probs + NLL ----
__global__ void k_out2(float* __restrict__ out, const float* __restrict__ bo,
                       const int* __restrict__ labels,
                       const float2* __restrict__ part,
                       float* __restrict__ acc) {
  __shared__ float sred[4];
  int i = blockIdx.x * 256 + threadIdx.x;   // 0..65535 = b*T + t
  float l0 = bo[0], l1 = bo[1];
#pragma unroll
  for (int hj = 0; hj < 16; ++hj) {
    float2 p = part[(size_t)hj * (BATCH * TLEN) + i];
    l0 += p.x; l1 += p.y;
  }
  float mx = fmaxf(l0, l1);
  float e0 = __expf(l0 - mx), e1 = __expf(l1 - mx);
  float s = e0 + e1, inv = 1.0f / s;
  out[(size_t)i * 2 + 0] = e0 * inv;
  out[(size_t)i * 2 + 1] = e1 * inv;
  int lab = labels[i];
  float nll = __logf(s) - ((lab ? l1 : l0) - mx);
#pragma unroll
  for (int off = 32; off >= 1; off >>= 1) nll += __shfl_xor(nll, off);
  if ((threadIdx.x & 63) == 0) sred[threadIdx.x >> 6] = nll;
  __syncthreads();
  if (threadIdx.x == 0)
    atomicAdd(acc, sred[0] + sred[1] + sred[2] + sred[3]);
}

__global__ void k_fin(const float* __restrict__ acc, float* __restrict__ out) {
  out[BATCH * TLEN * 2] = acc[0] * (1.0f / (float)(BATCH * TLEN));
}

extern "C" void kernel_launch(void* const* d_in, const int* in_sizes, int n_in,
                              void* d_out, int out_size, void* d_ws, size_t ws_size,
                              hipStream_t stream) {
  const float* x      = (const float*)d_in[0];
  const int*   labels = (const int*)d_in[1];
  const float* Wx     = (const float*)d_in[2];
  const float* Wh     = (const float*)d_in[3];
  const float* b      = (const float*)d_in[4];
  const float* Wo     = (const float*)d_in[5];
  const float* bo     = (const float*)d_in[6];
  float* out = (float*)d_out;
  char* ws = (char*)d_ws;

  unsigned short* Wt  = (unsigned short*)(ws + OFF_WT);
  unsigned short* xbf = (unsigned short*)(ws + OFF_XBF);
  unsigned*       hb  = (unsigned*)(ws + OFF_HB);
  float*          acc = (float*)(ws + OFF_ACC);
  float*          part = (float*)(ws + OFF_PART);

  // hb zero => h_0 = 0 with tag 0 (self-validating); acc zero
  hipMemsetAsync(ws + OFF_HB, 0, ZERO_LEN, stream);
  k_convx<<<8192, 256, 0, stream>>>((const float4*)x, (ushort4*)xbf);
  k_tw<<<640, 256, 0, stream>>>(Wx, Wh, Wt);
  k_lstm<<<128, 512, 0, stream>>>(xbf, Wt, b, Wo, hb, part);
  k_out2<<<256, 256, 0, stream>>>(out, bo, labels, (const float2*)part, acc);
  k_fin<<<1, 1, 0, stream>>>(acc, out);
}

// Round 10
// 2661.552 us; speedup vs baseline: 1.3692x; 1.0112x over previous
//
#include <hip/hip_runtime.h>
#include <stdint.h>

#define TLEN 1024
#define BATCH 64
#define DIMX 128
#define HID 512

typedef __attribute__((ext_vector_type(8))) short short8;
typedef __attribute__((ext_vector_type(4))) float f32x4;
typedef __attribute__((ext_vector_type(4))) unsigned u32x4;

// ---- workspace layout (bytes) ----
#define OFF_WT   0u           // Wt: [2048][640] bf16 = 2,621,440
#define OFF_XBF  2621440u     // xbf: [64][1024][128] bf16 = 16,777,216
#define OFF_HB   19398656u    // hb: [2][64][512] u32 (tagged bf16) = 262,144
#define OFF_ACC  19660800u    // acc: 64
#define OFF_PART 19660864u    // part: [16][64][1024][2] f32 = 8,388,608
#define ZERO_LEN 262208u      // hb + acc

__device__ __forceinline__ unsigned short f2bf(float f) {
  unsigned u = __float_as_uint(f);
  u += 0x7fffu + ((u >> 16) & 1u);
  return (unsigned short)(u >> 16);
}
__device__ __forceinline__ float sigm(float x) { return 1.0f / (1.0f + __expf(-x)); }
__device__ __forceinline__ float tanh_fast(float x) {
  float a = fabsf(x);
  float e = __expf(2.0f * a);
  float t = 1.0f - 2.0f / (e + 1.0f);
  return copysignf(t, x);
}

__device__ __forceinline__ bool tags_bad(const u32x4& r0, const u32x4& r1,
                                         const u32x4& r2, const u32x4& r3,
                                         unsigned tg) {
  unsigned d = (r0[0] ^ tg) | (r0[1] ^ tg) | (r0[2] ^ tg) | (r0[3] ^ tg);
  d |= (r1[0] ^ tg) | (r1[1] ^ tg) | (r1[2] ^ tg) | (r1[3] ^ tg);
  d |= (r2[0] ^ tg) | (r2[1] ^ tg) | (r2[2] ^ tg) | (r2[3] ^ tg);
  d |= (r3[0] ^ tg) | (r3[1] ^ tg) | (r3[2] ^ tg) | (r3[3] ^ tg);
  return (d & 0xFFFFu) != 0u;
}

// ---- x fp32 -> bf16, coalesced ----
__global__ void k_convx(const float4* __restrict__ x4, ushort4* __restrict__ o4) {
  int i = blockIdx.x * 256 + threadIdx.x;
  float4 v = x4[i];
  ushort4 o;
  o.x = f2bf(v.x); o.y = f2bf(v.y); o.z = f2bf(v.z); o.w = f2bf(v.w);
  o4[i] = o;
}

// ---- build Wt[col 0..2047][k 0..639] bf16 = concat(Wx;Wh)^T (proven) ----
__global__ void k_tw(const float* __restrict__ Wx, const float* __restrict__ Wh,
                     unsigned short* __restrict__ Wt) {
  __shared__ float tile[32][65];
  int bk = blockIdx.x;
  int k0 = (bk / 64) * 64;
  int c0 = (bk % 64) * 32;
  int tid = threadIdx.x;
  const float* src = (k0 < 128) ? (Wx + (size_t)k0 * 2048)
                                : (Wh + (size_t)(k0 - 128) * 2048);
#pragma unroll
  for (int p = 0; p < 8; ++p) {
    int i = p * 256 + tid;
    int kk = i >> 5, cc = i & 31;
    tile[cc][kk] = src[(size_t)kk * 2048 + (c0 + cc)];
  }
  __syncthreads();
  int cc = tid >> 3, ch = tid & 7;
  unsigned short tmp[8];
#pragma unroll
  for (int j = 0; j < 8; ++j) tmp[j] = f2bf(tile[cc][ch * 8 + j]);
  uint4 o;
  o.x = (unsigned)tmp[0] | ((unsigned)tmp[1] << 16);
  o.y = (unsigned)tmp[2] | ((unsigned)tmp[3] << 16);
  o.z = (unsigned)tmp[4] | ((unsigned)tmp[5] << 16);
  o.w = (unsigned)tmp[6] | ((unsigned)tmp[7] << 16);
  *(uint4*)(Wt + (size_t)(c0 + cc) * 640 + k0 + ch * 8) = o;
}

// ---- recurrence: 128 WGs = 8 groups(8 rows) x 16 WGs(512thr = 8 waves) ----
// R8 skeleton (proven 2633us) + spin-diet: only lanes m<8 (the non-duplicate
// half) load+check during the spin; __ballot counts active lanes only.
// After detect, 8 shuffles replicate packed row-7 frags into dup lanes.
// Halves poll LLC traffic and spin VALU; detect==data gate unchanged.
__global__ __launch_bounds__(512, 1) void k_lstm(
    const unsigned short* __restrict__ xbf,   // [B][T][D] bf16
    const unsigned short* __restrict__ Wt,    // [4H][640] bf16 (B^T layout)
    const float* __restrict__ bias,           // [4H]
    const float* __restrict__ Wo,             // [H][2]
    unsigned* __restrict__ hb,                // [2][B][H] tagged u32
    float* __restrict__ part)                 // [16][B][T][2] logit partials
{
  __shared__ float red[2][8][4][8][32];    // 64 KB (buf, kslice, gate, row, col)

  const int tid  = threadIdx.x;
  const int w    = tid >> 6;      // wave 0..7 = K-slice id
  const int lane = tid & 63;
  const int q    = lane >> 4;
  const int m    = lane & 15;
  const int grp  = blockIdx.x & 7;
  const int hj   = blockIdx.x >> 3;  // producer slice 0..15 (cols hj*32..+31)
  const int g0   = grp * 8;

  // ---- pin weight slice in registers ----
  short8 Bh[8][2];
  short8 Bx[8];
#pragma unroll
  for (int f = 0; f < 8; ++f) {
    int gate = f >> 1;
    int colg = gate * HID + hj * 32 + (f & 1) * 16 + m;
    const unsigned short* wc = Wt + (size_t)colg * 640;
#pragma unroll
    for (int c = 0; c < 2; ++c)
      Bh[f][c] = *(const short8*)(wc + 128 + w * 64 + c * 32 + q * 8);
    if (w < 4) Bx[f] = *(const short8*)(wc + w * 32 + q * 8);
  }

  // gate duty: wave w owns row w; lower half lanes own cols for i/f,
  // upper half same cols for g/o (split-serial-chain gates)
  const int col  = lane & 31;
  const int hcol = hj * 32 + col;
  const int up   = lane >> 5;          // 0 = i/f half, 1 = g/o half
  float c_state = 0.0f;
  const float b_a = up ? bias[2 * HID + hcol] : bias[0 * HID + hcol]; // zg : zi
  const float b_b = up ? bias[3 * HID + hcol] : bias[1 * HID + hcol]; // zo : zf
  const int ga = up ? 2 : 0;
  const int gb = up ? 3 : 1;
  const float2 wo = ((const float2*)Wo)[hcol];

  const int arow = (m < 8) ? m : 7;   // dup lanes clamp to row 7
  const int ab = g0 + arow;
  const int srcl = q * 16 + arow;     // shuffle source for frag replication
  // poll: wave w's own 64-col window at cols w*64 (2 producer WGs)
  const size_t poff = (size_t)ab * HID + w * 64 + q * 8;

  __syncthreads();

#pragma unroll 1
  for (int t = 0; t < TLEN; ++t) {
    const unsigned* hin = hb + (size_t)(t & 1) * (BATCH * HID);
    const int buf = t & 1;

    // ---- x chunk (issued before poll; latency hides under poll vmcnt) ----
    short8 a0;
    if (w < 4)
      a0 = *(const short8*)(xbf + ((size_t)ab * TLEN + t) * DIMX +
                            w * 32 + q * 8);

    // ---- own-window batched poll, detect==data; ONLY lanes m<8 spin ----
    const unsigned* pb = hin + poff;
    u32x4 r0 = {0,0,0,0}, r1 = {0,0,0,0}, r2 = {0,0,0,0}, r3 = {0,0,0,0};
    if (m < 8) {
      const unsigned tg = (unsigned)t & 0xFFFFu;
      int guard = 0;
      for (;;) {
        asm volatile(
            "global_load_dwordx4 %0, %4, off sc0 sc1\n\t"
            "global_load_dwordx4 %1, %4, off offset:16 sc0 sc1\n\t"
            "global_load_dwordx4 %2, %4, off offset:128 sc0 sc1\n\t"
            "global_load_dwordx4 %3, %4, off offset:144 sc0 sc1\n\t"
            "s_waitcnt vmcnt(0)"
            : "=v"(r0), "=v"(r1), "=v"(r2), "=v"(r3)
            : "v"(pb)
            : "memory");
        unsigned dq = (r0[0] ^ tg) | (r1[0] ^ tg) | (r2[0] ^ tg) | (r3[0] ^ tg);
        bool qbad = (dq & 0xFFFFu) != 0u;
        if (__ballot(qbad) == 0ull) {
          bool bad = tags_bad(r0, r1, r2, r3, tg);   // full check before ANY use
          if (__ballot(bad) == 0ull) break;
        }
        if (++guard > (1 << 20)) break;
        __builtin_amdgcn_s_sleep(1);
      }
    }

    // ---- pack own window -> 2 A-frags (valid in lanes m<8) ----
    union U4 { short8 s; unsigned u[4]; };
    U4 A0, A1;
    A0.u[0] = (r0[0] >> 16) | (r0[1] & 0xFFFF0000u);
    A0.u[1] = (r0[2] >> 16) | (r0[3] & 0xFFFF0000u);
    A0.u[2] = (r1[0] >> 16) | (r1[1] & 0xFFFF0000u);
    A0.u[3] = (r1[2] >> 16) | (r1[3] & 0xFFFF0000u);
    A1.u[0] = (r2[0] >> 16) | (r2[1] & 0xFFFF0000u);
    A1.u[1] = (r2[2] >> 16) | (r2[3] & 0xFFFF0000u);
    A1.u[2] = (r3[0] >> 16) | (r3[1] & 0xFFFF0000u);
    A1.u[3] = (r3[2] >> 16) | (r3[3] & 0xFFFF0000u);

    // ---- replicate row-7 frags into dup lanes (m>=8): 8 shuffles ----
#pragma unroll
    for (int j = 0; j < 4; ++j) {
      A0.u[j] = __shfl(A0.u[j], srcl);
      A1.u[j] = __shfl(A1.u[j], srcl);
    }
    short8 af0 = A0.s, af1 = A1.s;

    // ---- MFMA: partials for all 128 WG gate-cols over this K-slice ----
    f32x4 z[8];
#pragma unroll
    for (int f = 0; f < 8; ++f) z[f] = (f32x4){0.f, 0.f, 0.f, 0.f};
    if (w < 4) {
#pragma unroll
      for (int f = 0; f < 8; ++f)
        z[f] = __builtin_amdgcn_mfma_f32_16x16x32_bf16(a0, Bx[f], z[f], 0, 0, 0);
    }
#pragma unroll
    for (int f = 0; f < 8; ++f)
      z[f] = __builtin_amdgcn_mfma_f32_16x16x32_bf16(af0, Bh[f][0], z[f], 0, 0, 0);
#pragma unroll
    for (int f = 0; f < 8; ++f)
      z[f] = __builtin_amdgcn_mfma_f32_16x16x32_bf16(af1, Bh[f][1], z[f], 0, 0, 0);

    // ---- stage partials (valid rows in quads 0,1), double-buffered ----
    if (q < 2) {
#pragma unroll
      for (int f = 0; f < 8; ++f) {
#pragma unroll
        for (int r = 0; r < 4; ++r)
          red[buf][w][f >> 1][q * 4 + r][(f & 1) * 16 + m] = z[f][r];
      }
    }
    __syncthreads();   // the only WG rendezvous per step

    // ---- gates, split across half-waves: lower = i/f, upper = g/o ----
    {
      float za = b_a, zb = b_b;
#pragma unroll
      for (int jj = 0; jj < 8; ++jj) {
        za += red[buf][jj][ga][w][col];
        zb += red[buf][jj][gb][w][col];
      }
      // lower: va=ig, vb=fg ; upper: va=gg, vb=og
      float va = up ? tanh_fast(za) : sigm(za);
      float vb = sigm(zb);
      float gg = __shfl(va, col + 32);   // executed by all lanes
      float og = __shfl(vb, col + 32);

      if (lane < 32) {
        c_state = vb * c_state + va * gg;
        float hval = og * tanh_fast(c_state);

        // per-lane tagged store; 32 lanes = one 128B coalesced transaction
        unsigned hword = ((unsigned)f2bf(hval) << 16) |
                         (unsigned)((t + 1) & 0xFFFF);
        unsigned* dst = hb + (size_t)((t + 1) & 1) * (BATCH * HID) +
                        (size_t)(g0 + w) * HID + hcol;
        asm volatile("global_store_dword %0, %1, off sc0 sc1"
                     :: "v"(dst), "v"(hword) : "memory");

        // logit partial -> private slot (no atomics, no contention)
        float p0 = hval * wo.x, p1 = hval * wo.y;
        p0 += __shfl_xor(p0, 16); p1 += __shfl_xor(p1, 16);
        p0 += __shfl_xor(p0, 8);  p1 += __shfl_xor(p1, 8);
        p0 += __shfl_xor(p0, 4);  p1 += __shfl_xor(p1, 4);
        p0 += __shfl_xor(p0, 2);  p1 += __shfl_xor(p1, 2);
        p0 += __shfl_xor(p0, 1);  p1 += __shfl_xor(p1, 1);
        if (lane == 0) {
          float2 pv; pv.x = p0; pv.y = p1;
          *(float2*)(part + (((size_t)hj * BATCH + (g0 + w)) * TLEN + t) * 2) = pv;
        }
      }
    }
  }
}

// ---- partials -> logits -> softmax probs + NLL ----
__global__ void k_out2(float* __restrict__ out, const float* __restrict__ bo,
                       const int* __restrict__ labels,
                       const float2* __restrict__ part,
                       float* __restrict__ acc) {
  __shared__ float sred[4];
  int i = blockIdx.x * 256 + threadIdx.x;   // 0..65535 = b*T + t
  float l0 = bo[0], l1 = bo[1];
#pragma unroll
  for (int hj = 0; hj < 16; ++hj) {
    float2 p = part[(size_t)hj * (BATCH * TLEN) + i];
    l0 += p.x; l1 += p.y;
  }
  float mx = fmaxf(l0, l1);
  float e0 = __expf(l0 - mx), e1 = __expf(l1 - mx);
  float s = e0 + e1, inv = 1.0f / s;
  out[(size_t)i * 2 + 0] = e0 * inv;
  out[(size_t)i * 2 + 1] = e1 * inv;
  int lab = labels[i];
  float nll = __logf(s) - ((lab ? l1 : l0) - mx);
#pragma unroll
  for (int off = 32; off >= 1; off >>= 1) nll += __shfl_xor(nll, off);
  if ((threadIdx.x & 63) == 0) sred[threadIdx.x >> 6] = nll;
  __syncthreads();
  if (threadIdx.x == 0)
    atomicAdd(acc, sred[0] + sred[1] + sred[2] + sred[3]);
}

__global__ void k_fin(const float* __restrict__ acc, float* __restrict__ out) {
  out[BATCH * TLEN * 2] = acc[0] * (1.0f / (float)(BATCH * TLEN));
}

extern "C" void kernel_launch(void* const* d_in, const int* in_sizes, int n_in,
                              void* d_out, int out_size, void* d_ws, size_t ws_size,
                              hipStream_t stream) {
  const float* x      = (const float*)d_in[0];
  const int*   labels = (const int*)d_in[1];
  const float* Wx     = (const float*)d_in[2];
  const float* Wh     = (const float*)d_in[3];
  const float* b      = (const float*)d_in[4];
  const float* Wo     = (const float*)d_in[5];
  const float* bo     = (const float*)d_in[6];
  float* out = (float*)d_out;
  char* ws = (char*)d_ws;

  unsigned short* Wt  = (unsigned short*)(ws + OFF_WT);
  unsigned short* xbf = (unsigned short*)(ws + OFF_XBF);
  unsigned*       hb  = (unsigned*)(ws + OFF_HB);
  float*          acc = (float*)(ws + OFF_ACC);
  float*          part = (float*)(ws + OFF_PART);

  // hb zero => h_0 = 0 with tag 0 (self-validating); acc zero
  hipMemsetAsync(ws + OFF_HB, 0, ZERO_LEN, stream);
  k_convx<<<8192, 256, 0, stream>>>((const float4*)x, (ushort4*)xbf);
  k_tw<<<640, 256, 0, stream>>>(Wx, Wh, Wt);
  k_lstm<<<128, 512, 0, stream>>>(xbf, Wt, b, Wo, hb, part);
  k_out2<<<256, 256, 0, stream>>>(out, bo, labels, (const float2*)part, acc);
  k_fin<<<1, 1, 0, stream>>>(acc, out);
}